// Round 2
// baseline (1562.178 us; speedup 1.0000x reference)
//
#include <hip/hip_runtime.h>
#include <hip/hip_bf16.h>

#define EMB   2048
#define RANK  4
#define VOCAB 8192
#define NH    4
#define BATCH 256
#define NCOLS (VOCAB * RANK * RANK)   // 131072
#define EPS   1e-10f

// Guide-verified fragment types (cdna_hip_programming.md §3): short8 = 8 bf16.
typedef short  bfrag8 __attribute__((ext_vector_type(8)));
typedef float  f32x4  __attribute__((ext_vector_type(4)));

static __device__ __forceinline__ short f2bf(float f) {
    unsigned u = __builtin_bit_cast(unsigned, f);
    u += 0x7FFFu + ((u >> 16) & 1u);           // round-to-nearest-even
    return (short)(u >> 16);
}

// ---------------------------------------------------------------------------
// Kernel 1: alpha/beta — exact fp32 dots (tiny). One wave per batch row.
// ---------------------------------------------------------------------------
__global__ __launch_bounds__(64) void tjd_ab(
    const float* __restrict__ x, const float* __restrict__ wa,
    const float* __restrict__ wb, float* __restrict__ alpha_ws,
    float* __restrict__ beta_ws)
{
    const int b = blockIdx.x;
    const int lane = threadIdx.x;
    const float4* wa4 = (const float4*)wa;   // (2048,4) row-major -> row = float4
    const float4* wb4 = (const float4*)wb;
    float pa[4] = {0.f, 0.f, 0.f, 0.f};
    float pb[4] = {0.f, 0.f, 0.f, 0.f};
    for (int k = lane; k < EMB; k += 64) {
        float xv = x[b * EMB + k];
        float4 a = wa4[k];
        float4 c = wb4[k];
        pa[0] += xv * a.x; pa[1] += xv * a.y; pa[2] += xv * a.z; pa[3] += xv * a.w;
        pb[0] += xv * c.x; pb[1] += xv * c.y; pb[2] += xv * c.z; pb[3] += xv * c.w;
    }
#pragma unroll
    for (int r = 0; r < 4; ++r) {
        float s = pa[r];
#pragma unroll
        for (int off = 1; off < 64; off <<= 1) s += __shfl_xor(s, off);
        if (lane == 0) alpha_ws[b * 4 + r] = fmaxf(s, 0.f) + EPS;
        float t = pb[r];
#pragma unroll
        for (int off = 1; off < 64; off <<= 1) t += __shfl_xor(t, off);
        if (lane == 0) beta_ws[b * 4 + r] = fmaxf(t, 0.f) + EPS;
    }
}

// ---------------------------------------------------------------------------
// Kernel 2: fused bf16-MFMA GEMM (x @ w_vocab) + relu + cm reduction + sel gather
// Tile: 128x128, BK=32, 256 threads (4 waves, 2x2 of 64x64 quadrants).
// ---------------------------------------------------------------------------
#define LDP 40   // LDS pitch in bf16 elems (odd mult of 8 -> 16B aligned, balanced banks)

__global__ __launch_bounds__(256) void tjd_gemm(
    const float* __restrict__ x, const float* __restrict__ w,
    const int* __restrict__ idx, float* __restrict__ cm_ws,
    float* __restrict__ sel_ws)
{
    __shared__ __align__(16) short As[128][LDP];   // As[m][k]
    __shared__ __align__(16) short Bs[128][LDP];   // Bs[n][k]  (transposed)
    __shared__ int match_cnt;
    __shared__ int match_data[512];

    const int tid  = threadIdx.x;
    const int lane = tid & 63;
    const int wv   = tid >> 6;
    const int wr   = wv >> 1;          // wave row (m)  0..1
    const int wc   = wv & 1;           // wave col (n)  0..1
    const int m0   = blockIdx.x * 128;
    const int n0   = blockIdx.y * 128;
    const int v0   = (n0 >> 2) & (VOCAB - 1);   // vocab window start (32 values)
    const int r1   = n0 >> 15;                  // which RANK-row block

    // --- scan indices for vocab hits inside this block's window -------------
    if (tid == 0) match_cnt = 0;
    __syncthreads();
    for (int e = tid; e < 512; e += 256) {
        int bl = e >> 2, h = e & 3;
        int v  = idx[(m0 + bl) * NH + h];
        unsigned vl = (unsigned)(v - v0);
        if (vl < 32u) {
            int slot = atomicAdd(&match_cnt, 1);
            match_data[slot] = (bl << 16) | (h << 8) | (int)vl;
        }
    }

    const f32x4 zero4 = {0.f, 0.f, 0.f, 0.f};
    f32x4 acc[4][4];
#pragma unroll
    for (int mt = 0; mt < 4; ++mt)
#pragma unroll
        for (int nt = 0; nt < 4; ++nt) acc[mt][nt] = zero4;

    const int frag_row = (lane & 15);
    const int frag_kg  = (lane >> 4);

    for (int kt = 0; kt < EMB / 32; ++kt) {
        const int k0 = kt * 32;
        __syncthreads();
        // stage A: 512 chunks of (m, 8k)
#pragma unroll
        for (int cc = 0; cc < 2; ++cc) {
            int c = tid + cc * 256;
            int m = c >> 2, f8 = c & 3;
            const float* src = x + (size_t)(m0 + m) * EMB + k0 + f8 * 8;
            float4 a0 = *(const float4*)src;
            float4 a1 = *(const float4*)(src + 4);
            bfrag8 h;
            h[0] = f2bf(a0.x); h[1] = f2bf(a0.y); h[2] = f2bf(a0.z); h[3] = f2bf(a0.w);
            h[4] = f2bf(a1.x); h[5] = f2bf(a1.y); h[6] = f2bf(a1.z); h[7] = f2bf(a1.w);
            *(bfrag8*)&As[m][f8 * 8] = h;
        }
        // stage B transposed: 512 chunks of (n, 8k); coalesced dword loads
#pragma unroll
        for (int cc = 0; cc < 2; ++cc) {
            int c = tid + cc * 256;
            int n = c & 127, kc8 = c >> 7;
            const float* src = w + (size_t)(k0 + kc8 * 8) * NCOLS + n0 + n;
            bfrag8 h;
#pragma unroll
            for (int j = 0; j < 8; ++j) h[j] = f2bf(src[(size_t)j * NCOLS]);
            *(bfrag8*)&Bs[n][kc8 * 8] = h;
        }
        __syncthreads();

        bfrag8 af[4], bfr[4];
#pragma unroll
        for (int mt = 0; mt < 4; ++mt)
            af[mt] = *(const bfrag8*)&As[wr * 64 + mt * 16 + frag_row][frag_kg * 8];
#pragma unroll
        for (int nt = 0; nt < 4; ++nt)
            bfr[nt] = *(const bfrag8*)&Bs[wc * 64 + nt * 16 + frag_row][frag_kg * 8];
#pragma unroll
        for (int mt = 0; mt < 4; ++mt)
#pragma unroll
            for (int nt = 0; nt < 4; ++nt)
                acc[mt][nt] = __builtin_amdgcn_mfma_f32_16x16x32_bf16(
                    af[mt], bfr[nt], acc[mt][nt], 0, 0, 0);
    }

    // --- epilogue 1: cm partial sums -----------------------------------------
    // C/D layout: col = lane&15, row = (lane>>4)*4 + reg. r2 = col%4 = lane&3.
    const int lane_hi = lane >> 4;
    const int r2 = lane & 3;
#pragma unroll
    for (int mt = 0; mt < 4; ++mt) {
#pragma unroll
        for (int reg = 0; reg < 4; ++reg) {
            float s = 0.f;
#pragma unroll
            for (int nt = 0; nt < 4; ++nt) s += fmaxf(acc[mt][nt][reg], 0.f);
            s += __shfl_xor(s, 4);
            s += __shfl_xor(s, 8);
            if (((lane >> 2) & 3) == 0) {
                int m_g = m0 + wr * 64 + mt * 16 + lane_hi * 4 + reg;
                atomicAdd(&cm_ws[(m_g * 4 + r1) * 4 + r2], s);
            }
        }
    }

    // --- epilogue 2: gather selected entries ---------------------------------
    int nmatch = match_cnt;
#pragma unroll
    for (int mt = 0; mt < 4; ++mt) {
#pragma unroll
        for (int nt = 0; nt < 4; ++nt) {
            for (int i = 0; i < nmatch; ++i) {
                int md = match_data[i];
                int bl = md >> 16, h = (md >> 8) & 0xFF, vl = md & 0xFF;
                if ((bl >> 6) != wr) continue;
                int r64 = bl & 63;
                if ((r64 >> 4) != mt) continue;
                int ncol = vl * 4;                 // block-local col for r2=0
                if ((ncol >> 6) != wc) continue;
                int nw = ncol & 63;
                if ((nw >> 4) != nt) continue;
                int need_hi = (r64 >> 2) & 3;
                int reg = r64 & 3;
                int cbase = nw & 15;               // 0,4,8,12
                if (lane_hi == need_hi && ((lane & 15) >> 2) == (cbase >> 2)) {
                    float val = (reg == 0) ? acc[mt][nt][0]
                              : (reg == 1) ? acc[mt][nt][1]
                              : (reg == 2) ? acc[mt][nt][2]
                                           : acc[mt][nt][3];
                    val = fmaxf(val, 0.f) + EPS;
                    sel_ws[(((m0 + bl) * NH + h) * 4 + r1) * 4 + r2] = val;
                }
            }
        }
    }
}

// ---------------------------------------------------------------------------
// Kernel 3: per-batch 4x4 chains + logs. One thread per batch row.
// ---------------------------------------------------------------------------
static __device__ __forceinline__ void matmul4(const float a[4][4],
                                               const float b[4][4],
                                               float o[4][4]) {
#pragma unroll
    for (int i = 0; i < 4; ++i)
#pragma unroll
        for (int j = 0; j < 4; ++j) {
            float s = 0.f;
#pragma unroll
            for (int k = 0; k < 4; ++k) s += a[i][k] * b[k][j];
            o[i][j] = s;
        }
}

__global__ __launch_bounds__(64) void tjd_final(
    const float* __restrict__ cm_ws, const float* __restrict__ alpha_ws,
    const float* __restrict__ beta_ws, const float* __restrict__ sel_ws,
    float* __restrict__ out)
{
    int b = blockIdx.x * 64 + threadIdx.x;
    if (b >= BATCH) return;

    float cm[4][4];
#pragma unroll
    for (int i = 0; i < 4; ++i)
#pragma unroll
        for (int j = 0; j < 4; ++j)
            cm[i][j] = cm_ws[(b * 4 + i) * 4 + j] + (float)VOCAB * EPS;

    float z[4][4], t[4][4];
#pragma unroll
    for (int i = 0; i < 4; ++i)
#pragma unroll
        for (int j = 0; j < 4; ++j) z[i][j] = cm[i][j];
    for (int it = 0; it < NH - 1; ++it) {
        matmul4(z, cm, t);
#pragma unroll
        for (int i = 0; i < 4; ++i)
#pragma unroll
            for (int j = 0; j < 4; ++j) z[i][j] = t[i][j];
    }

    float m[4][4], s[4][4];
#pragma unroll
    for (int i = 0; i < 4; ++i)
#pragma unroll
        for (int j = 0; j < 4; ++j)
            m[i][j] = sel_ws[((b * NH + 0) * 4 + i) * 4 + j];
    for (int h = 1; h < NH; ++h) {
#pragma unroll
        for (int i = 0; i < 4; ++i)
#pragma unroll
            for (int j = 0; j < 4; ++j)
                s[i][j] = sel_ws[((b * NH + h) * 4 + i) * 4 + j];
        matmul4(m, s, t);
#pragma unroll
        for (int i = 0; i < 4; ++i)
#pragma unroll
            for (int j = 0; j < 4; ++j) m[i][j] = t[i][j];
    }

    float al[4], be[4];
#pragma unroll
    for (int i = 0; i < 4; ++i) { al[i] = alpha_ws[b * 4 + i]; be[i] = beta_ws[b * 4 + i]; }

    float p = 0.f, nc = 0.f;
#pragma unroll
    for (int i = 0; i < 4; ++i)
#pragma unroll
        for (int j = 0; j < 4; ++j) {
            p  += al[i] * m[i][j] * be[j];
            nc += al[i] * z[i][j] * be[j];
        }
    out[b] = logf(nc) - logf(p);
}

// ---------------------------------------------------------------------------
// Workspace layout (floats):
//   cm_ws    : [0,        4096)   BATCH*16, zeroed each launch
//   alpha_ws : [4096,     5120)   BATCH*4
//   beta_ws  : [5120,     6144)   BATCH*4
//   sel_ws   : [6144,    22528)   BATCH*NH*16 = 16384
// Total: 22528 floats = 90112 bytes.
// ---------------------------------------------------------------------------
extern "C" void kernel_launch(void* const* d_in, const int* in_sizes, int n_in,
                              void* d_out, int out_size, void* d_ws, size_t ws_size,
                              hipStream_t stream) {
    (void)in_sizes; (void)n_in; (void)out_size; (void)ws_size;
    const float* x  = (const float*)d_in[0];
    const float* wa = (const float*)d_in[1];
    const float* wb = (const float*)d_in[2];
    const float* wv = (const float*)d_in[3];
    const int*   ix = (const int*)d_in[4];
    float* out = (float*)d_out;

    float* ws       = (float*)d_ws;
    float* cm_ws    = ws;
    float* alpha_ws = ws + 4096;
    float* beta_ws  = ws + 5120;
    float* sel_ws   = ws + 6144;

    hipMemsetAsync(cm_ws, 0, 4096 * sizeof(float), stream);
    tjd_ab<<<dim3(BATCH), dim3(64), 0, stream>>>(x, wa, wb, alpha_ws, beta_ws);
    tjd_gemm<<<dim3(2, NCOLS / 128), dim3(256), 0, stream>>>(x, wv, ix, cm_ws, sel_ws);
    tjd_final<<<dim3(BATCH / 64), dim3(64), 0, stream>>>(cm_ws, alpha_ws, beta_ws, sel_ws, out);
}